// Round 6
// baseline (385.947 us; speedup 1.0000x reference)
//
#include <hip/hip_runtime.h>

#define B_ 16
#define ORDER_ 2
#define N_ 512
#define D_ 128
#define H_ 8

// ws: xp bf16 for all 64 instances = 8,388,608 B. h staged in d_out.

__device__ __forceinline__ unsigned short f2bf(float f) {
    unsigned int u = __float_as_uint(f);
    u += 0x7fffu + ((u >> 16) & 1u);
    return (unsigned short)(u >> 16);
}
__device__ __forceinline__ float bflo(unsigned int u) { return __uint_as_float(u << 16); }
__device__ __forceinline__ float bfhi(unsigned int u) { return __uint_as_float(u & 0xffff0000u); }

// ---------------------------------------------------------------------------
// Kernel 1: xp[inst,n,col] = sum_c x[bi,n,c]*W[ij,col,c] + pb[ij,col], bf16 out.
// ---------------------------------------------------------------------------
#define PITCHF 66
__global__ __launch_bounds__(256) void proj_kernel(
    const float* __restrict__ x,
    const float* __restrict__ W,
    const float* __restrict__ pb,
    unsigned short* __restrict__ xp)
{
    __shared__ float xt[32 * PITCHF];
    __shared__ float wt[32 * PITCHF];
    const int rt = blockIdx.x;
    const int ct = blockIdx.y;
    const int inst = blockIdx.z;
    const int j = inst & 1;
    const int bi = inst >> 1;
    const int ij = (bi & 1) * 2 + j;
    const int n0 = rt * 64;
    const int col0 = ct * 64;
    const int t = threadIdx.x;

    const float* xs   = x + ((size_t)bi * N_ + n0) * D_;
    const float* wsrc = W + ((size_t)ij * D_ + col0) * D_;

    const int tc = (t & 15) * 4;
    const int tr = (t >> 4) * 4;
    float acc[4][4];
#pragma unroll
    for (int a = 0; a < 4; ++a)
#pragma unroll
        for (int b = 0; b < 4; ++b) acc[a][b] = 0.f;

    for (int c0 = 0; c0 < D_; c0 += 32) {
        for (int idx = t; idx < 64 * 32; idx += 256) {
            const int r = idx >> 5, c = idx & 31;
            xt[c * PITCHF + r] = xs[(size_t)r * D_ + c0 + c];
            wt[c * PITCHF + r] = wsrc[(size_t)r * D_ + c0 + c];
        }
        __syncthreads();
#pragma unroll 8
        for (int c = 0; c < 32; ++c) {
            const float2 xa = *(const float2*)&xt[c * PITCHF + tr];
            const float2 xb = *(const float2*)&xt[c * PITCHF + tr + 2];
            const float2 wa = *(const float2*)&wt[c * PITCHF + tc];
            const float2 wb = *(const float2*)&wt[c * PITCHF + tc + 2];
            const float xf[4] = { xa.x, xa.y, xb.x, xb.y };
            const float wf[4] = { wa.x, wa.y, wb.x, wb.y };
#pragma unroll
            for (int a = 0; a < 4; ++a)
#pragma unroll
                for (int b = 0; b < 4; ++b) acc[a][b] += xf[a] * wf[b];
        }
        __syncthreads();
    }

    float pbv[4];
#pragma unroll
    for (int b = 0; b < 4; ++b) pbv[b] = pb[ij * D_ + col0 + tc + b];
#pragma unroll
    for (int a = 0; a < 4; ++a) {
        const unsigned int p0 = f2bf(acc[a][0] + pbv[0]) | ((unsigned int)f2bf(acc[a][1] + pbv[1]) << 16);
        const unsigned int p1 = f2bf(acc[a][2] + pbv[2]) | ((unsigned int)f2bf(acc[a][3] + pbv[3]) << 16);
        uint2 pk = { p0, p1 };
        *(uint2*)&xp[(((size_t)inst * N_) + n0 + tr + a) * D_ + col0 + tc] = pk;
    }
}

// ---------------------------------------------------------------------------
// Kernel 2: attention. Block = (bi, 32-dst tile). Thread = (dstq 0..7, h 0..7,
// fq 0..3): owns 4 dst x 4 feats of head h. Per src it computes the exp for
// its OWN dst (dstq*4+fq) and gets the other 3 w's from lanes t^1,t^2,t^3 via
// __shfl_xor (those lanes share (dstq,h)). acc slot k corresponds to dst
// dstq*4 + (fq^k). Z is per-thread register state (owner: slot 0), gathered
// by shuffles in the epilogue. Double-buffered LDS staging, ONE barrier per
// chunk: store(c+2)->buf[c&1] can only happen after sync(c+1), which every
// wave reaches only after finishing compute(c) -> no race.
// Masked entries: w = exp(0) = 1; softmax over all 512 src.
// ---------------------------------------------------------------------------
__global__ __launch_bounds__(256) void attn_kernel(
    const unsigned short* __restrict__ xp,
    const int* __restrict__ A,
    const float* __restrict__ att_src,
    const float* __restrict__ att_dst,
    const float* __restrict__ bias,
    float* __restrict__ hout)
{
    __shared__ unsigned short xh_l[2][16 * 128];   // 8 KB raw bf16 chunks
    __shared__ int   A_l[2][16 * 32];              // 4 KB
    __shared__ float ss_all[N_ * 8];               // 16 KB [s][h]
    __shared__ float as_l[128];
    __shared__ float ad_l[128];

    const int tile = blockIdx.x;   // 0..15
    const int bi   = blockIdx.y;   // 0..31
    const int i_ = bi & 1;
    const int d0 = tile * 32;
    const int t = threadIdx.x;

    const int dstq = t >> 5;        // 0..7
    const int h    = (t >> 2) & 7;  // 0..7
    const int fq   = t & 3;         // 0..3
    const int myd  = dstq * 4 + fq; // own dst (local)
    const int f0   = h * 16 + fq * 4;

    const int* Ab = A + (size_t)bi * N_ * N_;

    float hacc[16];
#pragma unroll
    for (int m = 0; m < 16; ++m) hacc[m] = 0.f;

    for (int j = 0; j < 2; ++j) {
        const int inst = bi * 2 + j;
        const int ij = i_ * 2 + j;
        const unsigned short* xpi = xp + (size_t)inst * N_ * D_;
        const int aedge = j ? 3 : 2;

        __syncthreads();             // prev conv fully done with LDS
        if (t < 128) {
            as_l[t] = att_src[ij * D_ + t];
            ad_l[t] = att_dst[ij * D_ + t];
        }
        __syncthreads();

        // ss for all 512 src: thread = (sh = t&7, sbase = t>>3), 16 rows each
        {
            const int sh = t & 7;
            const int sbase = t >> 3;
#pragma unroll 4
            for (int m = 0; m < 16; ++m) {
                const int s = sbase + 32 * m;
                const unsigned short* xr = xpi + (size_t)s * D_ + sh * 16;
                const uint4 b0 = *(const uint4*)xr;
                const uint4 b1 = *(const uint4*)(xr + 8);
                const float xv[16] = {
                    bflo(b0.x), bfhi(b0.x), bflo(b0.y), bfhi(b0.y),
                    bflo(b0.z), bfhi(b0.z), bflo(b0.w), bfhi(b0.w),
                    bflo(b1.x), bfhi(b1.x), bflo(b1.y), bfhi(b1.y),
                    bflo(b1.z), bfhi(b1.z), bflo(b1.w), bfhi(b1.w) };
                float ssv = 0.f;
#pragma unroll
                for (int k = 0; k < 16; ++k) ssv += xv[k] * as_l[sh * 16 + k];
                ss_all[s * 8 + sh] = ssv;
            }
        }
        // sd for own (d0+myd, h)
        float sd = 0.f;
        {
            const unsigned short* xr = xpi + (size_t)(d0 + myd) * D_ + h * 16;
            const uint4 b0 = *(const uint4*)xr;
            const uint4 b1 = *(const uint4*)(xr + 8);
            const float xv[16] = {
                bflo(b0.x), bfhi(b0.x), bflo(b0.y), bfhi(b0.y),
                bflo(b0.z), bfhi(b0.z), bflo(b0.w), bfhi(b0.w),
                bflo(b1.x), bfhi(b1.x), bflo(b1.y), bfhi(b1.y),
                bflo(b1.z), bfhi(b1.z), bflo(b1.w), bfhi(b1.w) };
#pragma unroll
            for (int k = 0; k < 16; ++k) sd += xv[k] * ad_l[h * 16 + k];
        }

        // prefetch chunk 0
        int4  pA;
        uint4 pX;
        if (t < 128)
            pA = *(const int4*)&Ab[(size_t)(t >> 3) * N_ + d0 + (t & 7) * 4];
        pX = *(const uint4*)(xpi + (size_t)(t >> 4) * D_ + (t & 15) * 8);

        float acc[16];
#pragma unroll
        for (int m = 0; m < 16; ++m) acc[m] = 0.f;
        float zacc = 0.f;

        for (int c = 0; c < 32; ++c) {
            const int buf = c & 1;
            const int s0 = c * 16;
            // store prefetched chunk
            if (t < 128)
                *(int4*)&A_l[buf][(t >> 3) * 32 + (t & 7) * 4] = pA;
            *(uint4*)&xh_l[buf][(t >> 4) * 128 + (t & 15) * 8] = pX;
            // prefetch next chunk
            if (c < 31) {
                const int s0n = s0 + 16;
                if (t < 128)
                    pA = *(const int4*)&Ab[(size_t)(s0n + (t >> 3)) * N_ + d0 + (t & 7) * 4];
                pX = *(const uint4*)(xpi + (size_t)(s0n + (t >> 4)) * D_ + (t & 15) * 8);
            }
            __syncthreads();   // buf visible (also covers ss_all on c==0)
#pragma unroll
            for (int sl = 0; sl < 16; ++sl) {
                const int a = A_l[buf][sl * 32 + myd];
                const bool edge = (a == 4) || (a == aedge);
                const float z0 = ss_all[(s0 + sl) * 8 + h] + sd;
                const float zr = z0 >= 0.f ? z0 : 0.2f * z0;
                const float w = edge ? __expf(zr) : 1.0f;
                zacc += w;
                const float v1 = __shfl_xor(w, 1);
                const float v2 = __shfl_xor(w, 2);
                const float v3 = __shfl_xor(v1, 2);
                const uint2 xb = *(const uint2*)&xh_l[buf][sl * 128 + f0];
                const float x0 = bflo(xb.x), x1 = bfhi(xb.x);
                const float x2 = bflo(xb.y), x3 = bfhi(xb.y);
                acc[0]  += w  * x0; acc[1]  += w  * x1; acc[2]  += w  * x2; acc[3]  += w  * x3;
                acc[4]  += v1 * x0; acc[5]  += v1 * x1; acc[6]  += v1 * x2; acc[7]  += v1 * x3;
                acc[8]  += v2 * x0; acc[9]  += v2 * x1; acc[10] += v2 * x2; acc[11] += v2 * x3;
                acc[12] += v3 * x0; acc[13] += v3 * x1; acc[14] += v3 * x2; acc[15] += v3 * x3;
            }
        }

        // epilogue: gather Z for all 4 slots, add self-loop + bias
        const float z1 = __shfl_xor(zacc, 1);
        const float z2 = __shfl_xor(zacc, 2);
        const float z3 = __shfl_xor(z1, 2);
        const float Zi[4] = { 1.0f / zacc, 1.0f / z1, 1.0f / z2, 1.0f / z3 };
        const float* bp = bias + ij * D_ + f0;
        const float bv[4] = { bp[0], bp[1], bp[2], bp[3] };
#pragma unroll
        for (int slot = 0; slot < 4; ++slot) {
            const int dst = d0 + dstq * 4 + (fq ^ slot);
            const unsigned short* xr = xpi + (size_t)dst * D_ + f0;
            const uint2 xb = *(const uint2*)xr;
            hacc[slot * 4 + 0] += acc[slot * 4 + 0] * Zi[slot] + bflo(xb.x) + bv[0];
            hacc[slot * 4 + 1] += acc[slot * 4 + 1] * Zi[slot] + bfhi(xb.x) + bv[1];
            hacc[slot * 4 + 2] += acc[slot * 4 + 2] * Zi[slot] + bflo(xb.y) + bv[2];
            hacc[slot * 4 + 3] += acc[slot * 4 + 3] * Zi[slot] + bfhi(xb.y) + bv[3];
        }
    }

#pragma unroll
    for (int slot = 0; slot < 4; ++slot) {
        const int dst = d0 + dstq * 4 + (fq ^ slot);
        float* hp = hout + (((size_t)bi * N_) + dst) * D_ + f0;
        float4 o = { hacc[slot * 4 + 0], hacc[slot * 4 + 1],
                     hacc[slot * 4 + 2], hacc[slot * 4 + 3] };
        *(float4*)hp = o;
    }
}

// ---------------------------------------------------------------------------
// Kernel 3: in-place mix on d_out (thread owns both i slices of one b).
// ---------------------------------------------------------------------------
__global__ __launch_bounds__(256) void combine_kernel(float* __restrict__ h)
{
    const int idx = blockIdx.x * 256 + threadIdx.x;
    const int b = idx >> 14;
    const int r = idx & 16383;
    float4* p0 = (float4*)h + (size_t)b * 32768 + r;
    float4* p1 = p0 + 16384;
    const float4 a = *p0;
    const float4 o = *p1;
    float4 r0, r1;
    r0.x = 1.5f * a.x + 0.5f * o.x;  r1.x = 1.5f * o.x + 0.5f * a.x;
    r0.y = 1.5f * a.y + 0.5f * o.y;  r1.y = 1.5f * o.y + 0.5f * a.y;
    r0.z = 1.5f * a.z + 0.5f * o.z;  r1.z = 1.5f * o.z + 0.5f * a.z;
    r0.w = 1.5f * a.w + 0.5f * o.w;  r1.w = 1.5f * o.w + 0.5f * a.w;
    *p0 = r0;
    *p1 = r1;
}

extern "C" void kernel_launch(void* const* d_in, const int* in_sizes, int n_in,
                              void* d_out, int out_size, void* d_ws, size_t ws_size,
                              hipStream_t stream)
{
    const float* x   = (const float*)d_in[0];
    const int*   A   = (const int*)d_in[1];
    const float* W   = (const float*)d_in[2];
    const float* pb  = (const float*)d_in[3];
    const float* as_ = (const float*)d_in[4];
    const float* ad_ = (const float*)d_in[5];
    const float* bs  = (const float*)d_in[6];

    unsigned short* xp = (unsigned short*)d_ws;   // 8,388,608 B
    float* h = (float*)d_out;

    proj_kernel<<<dim3(8, 2, 64), 256, 0, stream>>>(x, W, pb, xp);
    attn_kernel<<<dim3(16, 32), 256, 0, stream>>>(xp, A, as_, ad_, bs, h);
    combine_kernel<<<1024, 256, 0, stream>>>(h);
}

// Round 7
// 190.133 us; speedup vs baseline: 2.0299x; 2.0299x over previous
//
#include <hip/hip_runtime.h>

#define B_ 16
#define ORDER_ 2
#define N_ 512
#define D_ 128
#define H_ 8

// ws: xp_t bf16 TRANSPOSED [inst][f=128][s=512] for all 64 instances
// = 8,388,608 B. h staged in d_out; combine mixes in place.

typedef __attribute__((ext_vector_type(8))) short short8;
typedef __attribute__((ext_vector_type(4))) float floatx4;

__device__ __forceinline__ unsigned short f2bf(float f) {
    unsigned int u = __float_as_uint(f);
    u += 0x7fffu + ((u >> 16) & 1u);
    return (unsigned short)(u >> 16);
}
__device__ __forceinline__ float bflo(unsigned int u) { return __uint_as_float(u << 16); }
__device__ __forceinline__ float bfhi(unsigned int u) { return __uint_as_float(u & 0xffff0000u); }
__device__ __forceinline__ float bf1(unsigned short s) { return __uint_as_float(((unsigned int)s) << 16); }

// ---------------------------------------------------------------------------
// Kernel 1: xp_t[inst, f, n] = sum_c x[bi,n,c]*W[ij,f,c] + pb[ij,f], bf16,
// TRANSPOSED output (f-major) so attention B-fragments are contiguous in s.
// ---------------------------------------------------------------------------
#define PITCHF 66
__global__ __launch_bounds__(256) void proj_kernel(
    const float* __restrict__ x,
    const float* __restrict__ W,
    const float* __restrict__ pb,
    unsigned short* __restrict__ xpt)
{
    __shared__ float xt[32 * PITCHF];
    __shared__ float wt[32 * PITCHF];
    const int rt = blockIdx.x;
    const int ct = blockIdx.y;
    const int inst = blockIdx.z;
    const int j = inst & 1;
    const int bi = inst >> 1;
    const int ij = (bi & 1) * 2 + j;
    const int n0 = rt * 64;
    const int col0 = ct * 64;
    const int t = threadIdx.x;

    const float* xs   = x + ((size_t)bi * N_ + n0) * D_;
    const float* wsrc = W + ((size_t)ij * D_ + col0) * D_;

    const int tc = (t & 15) * 4;
    const int tr = (t >> 4) * 4;
    float acc[4][4];
#pragma unroll
    for (int a = 0; a < 4; ++a)
#pragma unroll
        for (int b = 0; b < 4; ++b) acc[a][b] = 0.f;

    for (int c0 = 0; c0 < D_; c0 += 32) {
        for (int idx = t; idx < 64 * 32; idx += 256) {
            const int r = idx >> 5, c = idx & 31;
            xt[c * PITCHF + r] = xs[(size_t)r * D_ + c0 + c];
            wt[c * PITCHF + r] = wsrc[(size_t)r * D_ + c0 + c];
        }
        __syncthreads();
#pragma unroll 8
        for (int c = 0; c < 32; ++c) {
            const float2 xa = *(const float2*)&xt[c * PITCHF + tr];
            const float2 xb = *(const float2*)&xt[c * PITCHF + tr + 2];
            const float2 wa = *(const float2*)&wt[c * PITCHF + tc];
            const float2 wb = *(const float2*)&wt[c * PITCHF + tc + 2];
            const float xf[4] = { xa.x, xa.y, xb.x, xb.y };
            const float wf[4] = { wa.x, wa.y, wb.x, wb.y };
#pragma unroll
            for (int a = 0; a < 4; ++a)
#pragma unroll
                for (int b = 0; b < 4; ++b) acc[a][b] += xf[a] * wf[b];
        }
        __syncthreads();
    }

    float pbv[4];
#pragma unroll
    for (int b = 0; b < 4; ++b) pbv[b] = pb[ij * D_ + col0 + tc + b];
    // transposed store: for each of 4 f-cols, pack 4 consecutive n as bf16x4
#pragma unroll
    for (int b = 0; b < 4; ++b) {
        const unsigned int lo = f2bf(acc[0][b] + pbv[b]) | ((unsigned int)f2bf(acc[1][b] + pbv[b]) << 16);
        const unsigned int hi = f2bf(acc[2][b] + pbv[b]) | ((unsigned int)f2bf(acc[3][b] + pbv[b]) << 16);
        uint2 pk = { lo, hi };
        *(uint2*)&xpt[((size_t)inst * D_ + col0 + tc + b) * N_ + n0 + tr] = pk;
    }
}

// ---------------------------------------------------------------------------
// Kernel 2: attention via MFMA. Block = (bi, 32-dst tile), 4 waves; wave w
// owns heads {2w, 2w+1} x 2 dst16 tiles. Per 32-s chunk, per (h, dt):
// lane builds the w A-fragment IN-LANE (A[m=lane&15=dst][k=quad*8+idx=s],
// 8 exps) and MFMAs with B = xp_t[h*16+n][s0+quad*8..+8] (16B global load,
// B[k][n=lane&15=f]). No barriers in the K-loop. Staged per conv: ss (all
// 512 s), sd, edge bitmasks (1 uint per s covers the block's 32 dst).
// Masked entries: w = exp(0) = 1; softmax over all 512 src.
// C/D: col=lane&15 (f), row=quad*4+reg (dst) [m89-verified].
// ---------------------------------------------------------------------------
__global__ __launch_bounds__(256) void attn_kernel(
    const unsigned short* __restrict__ xpt,
    const int* __restrict__ A,
    const float* __restrict__ att_src,
    const float* __restrict__ att_dst,
    const float* __restrict__ bias,
    float* __restrict__ hout)
{
    __shared__ float ss_t[8][N_];            // 16 KB [h][s]
    __shared__ unsigned int mask_l[2][N_];   // 4 KB
    __shared__ float sd_l[8][32];
    __shared__ float z_l[8][32];
    __shared__ float as_l[128];
    __shared__ float ad_l[128];

    const int tile = blockIdx.x;   // 0..15
    const int bi   = blockIdx.y;   // 0..31
    const int i_ = bi & 1;
    const int d0 = tile * 32;
    const int t = threadIdx.x;
    const int wave = t >> 6;
    const int L = t & 63;
    const int n = L & 15;          // A: dst-in-16 / B: f-in-16 / C: f col
    const int q = L >> 4;          // quad

    // --- edge bitmasks for both convs, once per block ---
    for (int s = t; s < N_; s += 256) {
        const int* Ar = A + ((size_t)bi * N_ + s) * N_ + d0;
        unsigned int m0 = 0, m1 = 0;
#pragma unroll
        for (int g = 0; g < 8; ++g) {
            const int4 v = *(const int4*)(Ar + g * 4);
            const int k = g * 4;
            if (v.x == 2 || v.x == 4) m0 |= 1u << (k + 0);
            if (v.x == 3 || v.x == 4) m1 |= 1u << (k + 0);
            if (v.y == 2 || v.y == 4) m0 |= 1u << (k + 1);
            if (v.y == 3 || v.y == 4) m1 |= 1u << (k + 1);
            if (v.z == 2 || v.z == 4) m0 |= 1u << (k + 2);
            if (v.z == 3 || v.z == 4) m1 |= 1u << (k + 2);
            if (v.w == 2 || v.w == 4) m0 |= 1u << (k + 3);
            if (v.w == 3 || v.w == 4) m1 |= 1u << (k + 3);
        }
        mask_l[0][s] = m0;
        mask_l[1][s] = m1;
    }

    float hacc[4][4];   // [hh2*2+dt][reg]
#pragma unroll
    for (int a = 0; a < 4; ++a)
#pragma unroll
        for (int b = 0; b < 4; ++b) hacc[a][b] = 0.f;

    for (int j = 0; j < 2; ++j) {
        const int inst = bi * 2 + j;
        const int ij = i_ * 2 + j;
        const unsigned short* xpi = xpt + (size_t)inst * D_ * N_;

        __syncthreads();                   // prev conv done with ss_t/sd_l
        if (t < 128) {
            as_l[t] = att_src[ij * D_ + t];
            ad_l[t] = att_dst[ij * D_ + t];
        }
        __syncthreads();

        // ss for all (h, s): thread = (hh = t>>5, 16-s range)
        {
            const int hh = t >> 5;
            const int sbase = (t & 31) * 16;
            float accs[16];
#pragma unroll
            for (int k = 0; k < 16; ++k) accs[k] = 0.f;
#pragma unroll 4
            for (int f = 0; f < 16; ++f) {
                const unsigned short* row = xpi + (size_t)(hh * 16 + f) * N_ + sbase;
                const uint4 a0 = *(const uint4*)row;
                const uint4 a1 = *(const uint4*)(row + 8);
                const float av = as_l[hh * 16 + f];
                accs[0]  += bflo(a0.x) * av; accs[1]  += bfhi(a0.x) * av;
                accs[2]  += bflo(a0.y) * av; accs[3]  += bfhi(a0.y) * av;
                accs[4]  += bflo(a0.z) * av; accs[5]  += bfhi(a0.z) * av;
                accs[6]  += bflo(a0.w) * av; accs[7]  += bfhi(a0.w) * av;
                accs[8]  += bflo(a1.x) * av; accs[9]  += bfhi(a1.x) * av;
                accs[10] += bflo(a1.y) * av; accs[11] += bfhi(a1.y) * av;
                accs[12] += bflo(a1.z) * av; accs[13] += bfhi(a1.z) * av;
                accs[14] += bflo(a1.w) * av; accs[15] += bfhi(a1.w) * av;
            }
#pragma unroll
            for (int k = 0; k < 16; ++k) ss_t[hh][sbase + k] = accs[k];
        }
        // sd for block's 32 dst: thread = (dd = t>>3, hh = t&7)
        {
            const int dd = t >> 3;
            const int hh = t & 7;
            float s = 0.f;
#pragma unroll
            for (int f = 0; f < 16; ++f)
                s += bf1(xpi[(size_t)(hh * 16 + f) * N_ + d0 + dd]) * ad_l[hh * 16 + f];
            sd_l[hh][dd] = s;
        }
        __syncthreads();                   // ss_t, sd_l, masks ready

        float sdv[2][2];
#pragma unroll
        for (int hh2 = 0; hh2 < 2; ++hh2)
#pragma unroll
            for (int dt = 0; dt < 2; ++dt)
                sdv[hh2][dt] = sd_l[wave * 2 + hh2][dt * 16 + n];

        floatx4 Cacc[2][2];
        float zacc[2][2];
#pragma unroll
        for (int a = 0; a < 2; ++a)
#pragma unroll
            for (int b = 0; b < 2; ++b) {
                Cacc[a][b] = (floatx4){0.f, 0.f, 0.f, 0.f};
                zacc[a][b] = 0.f;
            }

        // -------- barrier-free K loop: 16 chunks of 32 s --------
        for (int c = 0; c < 16; ++c) {
            const int s0 = c * 32;
            const int sq = s0 + q * 8;
            // B fragments for both heads (global, 16 B contiguous)
            short8 Bf[2];
#pragma unroll
            for (int hh2 = 0; hh2 < 2; ++hh2)
                Bf[hh2] = *(const short8*)(xpi + (size_t)((wave * 2 + hh2) * 16 + n) * N_ + sq);
            // mask words + ss (broadcast LDS reads, contiguous -> b128 merge)
            unsigned int mw[8];
#pragma unroll
            for (int idx = 0; idx < 8; ++idx) mw[idx] = mask_l[j][sq + idx];
            float ssv[2][8];
#pragma unroll
            for (int hh2 = 0; hh2 < 2; ++hh2)
#pragma unroll
                for (int idx = 0; idx < 8; ++idx)
                    ssv[hh2][idx] = ss_t[wave * 2 + hh2][sq + idx];
#pragma unroll
            for (int hh2 = 0; hh2 < 2; ++hh2) {
#pragma unroll
                for (int dt = 0; dt < 2; ++dt) {
                    const int bit = dt * 16 + n;
                    short8 Af;
#pragma unroll
                    for (int idx = 0; idx < 8; ++idx) {
                        const bool edge = (mw[idx] >> bit) & 1u;
                        const float z0 = ssv[hh2][idx] + sdv[hh2][dt];
                        const float zr = z0 >= 0.f ? z0 : 0.2f * z0;
                        const float w = edge ? __expf(zr) : 1.0f;
                        zacc[hh2][dt] += w;
                        Af[idx] = (short)f2bf(w);
                    }
                    Cacc[hh2][dt] = __builtin_amdgcn_mfma_f32_16x16x32_bf16(
                        Af, Bf[hh2], Cacc[hh2][dt], 0, 0, 0);
                }
            }
        }

        // Z: reduce over quads (lanes sharing dst = n), publish to LDS
#pragma unroll
        for (int hh2 = 0; hh2 < 2; ++hh2)
#pragma unroll
            for (int dt = 0; dt < 2; ++dt) {
                float z = zacc[hh2][dt];
                z += __shfl_xor(z, 16);
                z += __shfl_xor(z, 32);
                zacc[hh2][dt] = z;
            }
        __syncthreads();
        if (q == 0) {
#pragma unroll
            for (int hh2 = 0; hh2 < 2; ++hh2)
#pragma unroll
                for (int dt = 0; dt < 2; ++dt)
                    z_l[wave * 2 + hh2][dt * 16 + n] = zacc[hh2][dt];
        }
        __syncthreads();

        // epilogue: hacc += C/Z + xp_self + bias
#pragma unroll
        for (int hh2 = 0; hh2 < 2; ++hh2) {
            const int h = wave * 2 + hh2;
            const float bv = bias[ij * D_ + h * 16 + n];
#pragma unroll
            for (int dt = 0; dt < 2; ++dt) {
                const uint2 sv = *(const uint2*)(xpi + (size_t)(h * 16 + n) * N_ + d0 + dt * 16 + q * 4);
                const float selfv[4] = { bflo(sv.x), bfhi(sv.x), bflo(sv.y), bfhi(sv.y) };
#pragma unroll
                for (int reg = 0; reg < 4; ++reg) {
                    const float Zi = 1.0f / z_l[h][dt * 16 + q * 4 + reg];
                    hacc[hh2 * 2 + dt][reg] += Cacc[hh2][dt][reg] * Zi + selfv[reg] + bv;
                }
            }
        }
    }

    // store h (C layout: row dst = q*4+reg, col f = n)
#pragma unroll
    for (int hh2 = 0; hh2 < 2; ++hh2)
#pragma unroll
        for (int dt = 0; dt < 2; ++dt)
#pragma unroll
            for (int reg = 0; reg < 4; ++reg)
                hout[(((size_t)bi * N_) + d0 + dt * 16 + q * 4 + reg) * D_ +
                     (wave * 2 + hh2) * 16 + n] = hacc[hh2 * 2 + dt][reg];
}

// ---------------------------------------------------------------------------
// Kernel 3: in-place mix on d_out (thread owns both i slices of one b).
// ---------------------------------------------------------------------------
__global__ __launch_bounds__(256) void combine_kernel(float* __restrict__ h)
{
    const int idx = blockIdx.x * 256 + threadIdx.x;
    const int b = idx >> 14;
    const int r = idx & 16383;
    float4* p0 = (float4*)h + (size_t)b * 32768 + r;
    float4* p1 = p0 + 16384;
    const float4 a = *p0;
    const float4 o = *p1;
    float4 r0, r1;
    r0.x = 1.5f * a.x + 0.5f * o.x;  r1.x = 1.5f * o.x + 0.5f * a.x;
    r0.y = 1.5f * a.y + 0.5f * o.y;  r1.y = 1.5f * o.y + 0.5f * a.y;
    r0.z = 1.5f * a.z + 0.5f * o.z;  r1.z = 1.5f * o.z + 0.5f * a.z;
    r0.w = 1.5f * a.w + 0.5f * o.w;  r1.w = 1.5f * o.w + 0.5f * a.w;
    *p0 = r0;
    *p1 = r1;
}

extern "C" void kernel_launch(void* const* d_in, const int* in_sizes, int n_in,
                              void* d_out, int out_size, void* d_ws, size_t ws_size,
                              hipStream_t stream)
{
    const float* x   = (const float*)d_in[0];
    const int*   A   = (const int*)d_in[1];
    const float* W   = (const float*)d_in[2];
    const float* pb  = (const float*)d_in[3];
    const float* as_ = (const float*)d_in[4];
    const float* ad_ = (const float*)d_in[5];
    const float* bs  = (const float*)d_in[6];

    unsigned short* xpt = (unsigned short*)d_ws;   // 8,388,608 B
    float* h = (float*)d_out;

    proj_kernel<<<dim3(8, 2, 64), 256, 0, stream>>>(x, W, pb, xpt);
    attn_kernel<<<dim3(16, 32), 256, 0, stream>>>(xpt, A, as_, ad_, bs, h);
    combine_kernel<<<1024, 256, 0, stream>>>(h);
}

// Round 8
// 162.631 us; speedup vs baseline: 2.3731x; 1.1691x over previous
//
#include <hip/hip_runtime.h>

#define N_ 512
#define D_ 128
#define LOG2E 1.44269504088896f

// ws: xp_t bf16 TRANSPOSED [inst][f=128][s=512], 64 inst = 8,388,608 B.
// h staged in d_out; combine mixes in place.

typedef __attribute__((ext_vector_type(8))) short short8;
typedef __attribute__((ext_vector_type(4))) float floatx4;
typedef __attribute__((ext_vector_type(4))) unsigned int uintx4;

#if defined(__has_builtin)
#if __has_builtin(__builtin_amdgcn_exp2f)
#define EXP2F(x) __builtin_amdgcn_exp2f(x)
#else
#define EXP2F(x) exp2f(x)
#endif
#else
#define EXP2F(x) exp2f(x)
#endif

__device__ __forceinline__ unsigned short f2bf(float f) {
    unsigned int u = __float_as_uint(f);
    u += 0x7fffu + ((u >> 16) & 1u);
    return (unsigned short)(u >> 16);
}
__device__ __forceinline__ float bflo(unsigned int u) { return __uint_as_float(u << 16); }
__device__ __forceinline__ float bfhi(unsigned int u) { return __uint_as_float(u & 0xffff0000u); }
__device__ __forceinline__ float bf1(unsigned short s) { return __uint_as_float(((unsigned int)s) << 16); }

// ---------------------------------------------------------------------------
// Kernel 1: proj via MFMA. Block = (64-row ntile, inst), 4 waves; wave owns a
// 16-row mtile x 128 f. W[ij] staged once as bf16 in LDS (pitch 136 shorts:
// rows 16B-aligned, B-frag reads <=2-way banks); A-frags built in-lane from
// global fp32 x (RNE), no barriers after the single staging sync.
// xp_t[inst][f][n] = sum_c x[bi,n,c]*W[ij,f,c] + pb[ij,f], bf16 transposed.
// C/D: col=lane&15 (f-in-16), row=q*4+reg (n row) [m89-verified].
// ---------------------------------------------------------------------------
#define WPITCH 136
__global__ __launch_bounds__(256) void proj_kernel(
    const float* __restrict__ x,
    const float* __restrict__ W,
    const float* __restrict__ pb,
    unsigned short* __restrict__ xpt)
{
    __shared__ unsigned short wl[128 * WPITCH];   // 34 KB [f][c]
    const int ntile = blockIdx.x;   // 0..7 (64 rows)
    const int inst  = blockIdx.y;   // 0..63
    const int j = inst & 1;
    const int bi = inst >> 1;
    const int ij = (bi & 1) * 2 + j;
    const int t = threadIdx.x;
    const int wave = t >> 6, L = t & 63, n = L & 15, q = L >> 4;

    // stage W[ij] -> bf16 LDS: thread = (f = t>>1, 64-col half)
    {
        const int f = t >> 1, cb = (t & 1) * 64;
        const float* wr = W + ((size_t)ij * D_ + f) * D_ + cb;
        unsigned short* wd = wl + f * WPITCH + cb;
#pragma unroll
        for (int g = 0; g < 8; ++g) {
            const float4 v0 = *(const float4*)(wr + g * 8);
            const float4 v1 = *(const float4*)(wr + g * 8 + 4);
            uint4 pk;
            pk.x = f2bf(v0.x) | ((unsigned int)f2bf(v0.y) << 16);
            pk.y = f2bf(v0.z) | ((unsigned int)f2bf(v0.w) << 16);
            pk.z = f2bf(v1.x) | ((unsigned int)f2bf(v1.y) << 16);
            pk.w = f2bf(v1.z) | ((unsigned int)f2bf(v1.w) << 16);
            *(uint4*)(wd + g * 8) = pk;
        }
    }

    // A-frags: lane = row (n0w + n), k = q*8 + idx (fp32 global -> bf16)
    const int n0w = ntile * 64 + wave * 16;
    const float* xrow = x + ((size_t)bi * N_ + n0w + n) * D_ + q * 8;
    short8 Af[4];
#pragma unroll
    for (int kc = 0; kc < 4; ++kc) {
        const float4 a0 = *(const float4*)(xrow + kc * 32);
        const float4 a1 = *(const float4*)(xrow + kc * 32 + 4);
        uintx4 au;
        au.x = f2bf(a0.x) | ((unsigned int)f2bf(a0.y) << 16);
        au.y = f2bf(a0.z) | ((unsigned int)f2bf(a0.w) << 16);
        au.z = f2bf(a1.x) | ((unsigned int)f2bf(a1.y) << 16);
        au.w = f2bf(a1.z) | ((unsigned int)f2bf(a1.w) << 16);
        Af[kc] = __builtin_bit_cast(short8, au);
    }

    __syncthreads();   // W staged

#pragma unroll
    for (int ft = 0; ft < 8; ++ft) {
        floatx4 C = (floatx4){0.f, 0.f, 0.f, 0.f};
#pragma unroll
        for (int kc = 0; kc < 4; ++kc) {
            const short8 Bf = *(const short8*)(wl + (size_t)(ft * 16 + n) * WPITCH + kc * 32 + q * 8);
            C = __builtin_amdgcn_mfma_f32_16x16x32_bf16(Af[kc], Bf, C, 0, 0, 0);
        }
        const int fg = ft * 16 + n;
        const float pbv = pb[ij * D_ + fg];
        uint2 pk;
        pk.x = f2bf(C[0] + pbv) | ((unsigned int)f2bf(C[1] + pbv) << 16);
        pk.y = f2bf(C[2] + pbv) | ((unsigned int)f2bf(C[3] + pbv) << 16);
        *(uint2*)&xpt[((size_t)inst * D_ + fg) * N_ + n0w + q * 4] = pk;
    }
}

// ---------------------------------------------------------------------------
// Kernel 2: attention via MFMA. Block = (bi, 16-dst tile) -> 1024 blocks;
// 4 waves, wave owns 2 heads. Lane builds the w A-fragment in-lane
// (A[m=lane&15=dst][k=q*8+idx=s], 8 exp2 per MFMA) against B = xp_t rows
// (16B global loads). Scores pre-scaled by log2e -> raw v_exp_f32; w
// truncated to bf16 (v_and) so Z and the MFMA numerator use identical
// values; pairs packed with v_perm. No barriers in the K-loop.
// Masked entries: w = exp(0) = 1; softmax over all 512 src.
// ---------------------------------------------------------------------------
__global__ __launch_bounds__(256) void attn_kernel(
    const unsigned short* __restrict__ xpt,
    const int* __restrict__ A,
    const float* __restrict__ att_src,
    const float* __restrict__ att_dst,
    const float* __restrict__ bias,
    float* __restrict__ hout)
{
    __shared__ float ss_t[8][N_];            // 16 KB [h][s], log2-domain
    __shared__ unsigned int mask_l[2][N_];   // 4 KB (low 16 bits)
    __shared__ float sd_l[8][16];
    __shared__ float z_l[8][16];             // wave-private rows (h)
    __shared__ float as_l[128];
    __shared__ float ad_l[128];

    const int tile = blockIdx.x;   // 0..31
    const int bi   = blockIdx.y;   // 0..31
    const int i_ = bi & 1;
    const int d0 = tile * 16;
    const int t = threadIdx.x;
    const int wave = t >> 6, L = t & 63, n = L & 15, q = L >> 4;
    const int h0 = wave * 2;

    // edge bitmasks for both convs (bit k = dst d0+k)
#pragma unroll
    for (int rep = 0; rep < 2; ++rep) {
        const int s = t + rep * 256;
        const int* Ar = A + ((size_t)bi * N_ + s) * N_ + d0;
        unsigned int m0 = 0, m1 = 0;
#pragma unroll
        for (int g = 0; g < 4; ++g) {
            const int4 v = *(const int4*)(Ar + g * 4);
            const int k = g * 4;
            if (v.x == 2 || v.x == 4) m0 |= 1u << (k + 0);
            if (v.x == 3 || v.x == 4) m1 |= 1u << (k + 0);
            if (v.y == 2 || v.y == 4) m0 |= 1u << (k + 1);
            if (v.y == 3 || v.y == 4) m1 |= 1u << (k + 1);
            if (v.z == 2 || v.z == 4) m0 |= 1u << (k + 2);
            if (v.z == 3 || v.z == 4) m1 |= 1u << (k + 2);
            if (v.w == 2 || v.w == 4) m0 |= 1u << (k + 3);
            if (v.w == 3 || v.w == 4) m1 |= 1u << (k + 3);
        }
        mask_l[0][s] = m0;
        mask_l[1][s] = m1;
    }

    float hacc[2][4];
#pragma unroll
    for (int a = 0; a < 2; ++a)
#pragma unroll
        for (int b = 0; b < 4; ++b) hacc[a][b] = 0.f;

    for (int j = 0; j < 2; ++j) {
        const int inst = bi * 2 + j;
        const int ij = i_ * 2 + j;
        const unsigned short* xpi = xpt + (size_t)inst * D_ * N_;

        __syncthreads();             // prev conv done with ss_t/as_l/sd_l
        if (t < 128) {
            as_l[t] = att_src[ij * D_ + t] * LOG2E;
            ad_l[t] = att_dst[ij * D_ + t] * LOG2E;
        }
        __syncthreads();

        // ss (log2-domain) for all (h, s): thread = (hh = t>>5, 16-s range)
        {
            const int hh = t >> 5;
            const int sb = (t & 31) * 16;
            float accs[16];
#pragma unroll
            for (int k = 0; k < 16; ++k) accs[k] = 0.f;
#pragma unroll 4
            for (int f = 0; f < 16; ++f) {
                const unsigned short* row = xpi + (size_t)(hh * 16 + f) * N_ + sb;
                const uint4 a0 = *(const uint4*)row;
                const uint4 a1 = *(const uint4*)(row + 8);
                const float av = as_l[hh * 16 + f];
                accs[0]  += bflo(a0.x) * av; accs[1]  += bfhi(a0.x) * av;
                accs[2]  += bflo(a0.y) * av; accs[3]  += bfhi(a0.y) * av;
                accs[4]  += bflo(a0.z) * av; accs[5]  += bfhi(a0.z) * av;
                accs[6]  += bflo(a0.w) * av; accs[7]  += bfhi(a0.w) * av;
                accs[8]  += bflo(a1.x) * av; accs[9]  += bfhi(a1.x) * av;
                accs[10] += bflo(a1.y) * av; accs[11] += bfhi(a1.y) * av;
                accs[12] += bflo(a1.z) * av; accs[13] += bfhi(a1.z) * av;
                accs[14] += bflo(a1.w) * av; accs[15] += bfhi(a1.w) * av;
            }
#pragma unroll
            for (int k = 0; k < 16; ++k) ss_t[hh][sb + k] = accs[k];
        }
        // sd for block's 16 dst x 8 h
        if (t < 128) {
            const int dd = t >> 3;
            const int hh = t & 7;
            float s = 0.f;
#pragma unroll
            for (int f = 0; f < 16; ++f)
                s += bf1(xpi[(size_t)(hh * 16 + f) * N_ + d0 + dd]) * ad_l[hh * 16 + f];
            sd_l[hh][dd] = s;
        }
        __syncthreads();             // ss_t, sd_l ready

        const float sdv[2] = { sd_l[h0][n], sd_l[h0 + 1][n] };

        floatx4 Cacc[2] = { (floatx4){0.f,0.f,0.f,0.f}, (floatx4){0.f,0.f,0.f,0.f} };
        float zacc[2] = { 0.f, 0.f };

        // -------- barrier-free K loop: 16 chunks of 32 s --------
        for (int c = 0; c < 16; ++c) {
            const int sq = c * 32 + q * 8;
            short8 Bf[2];
            Bf[0] = *(const short8*)(xpi + (size_t)(h0 * 16 + n) * N_ + sq);
            Bf[1] = *(const short8*)(xpi + (size_t)((h0 + 1) * 16 + n) * N_ + sq);
            const uint4 m0v = *(const uint4*)&mask_l[j][sq];
            const uint4 m1v = *(const uint4*)&mask_l[j][sq + 4];
            const unsigned int mw[8] = { m0v.x, m0v.y, m0v.z, m0v.w,
                                         m1v.x, m1v.y, m1v.z, m1v.w };
#pragma unroll
            for (int hh2 = 0; hh2 < 2; ++hh2) {
                const float4 s0v = *(const float4*)&ss_t[h0 + hh2][sq];
                const float4 s1v = *(const float4*)&ss_t[h0 + hh2][sq + 4];
                const float ssv[8] = { s0v.x, s0v.y, s0v.z, s0v.w,
                                       s1v.x, s1v.y, s1v.z, s1v.w };
                unsigned int wt[8];
#pragma unroll
                for (int idx = 0; idx < 8; ++idx) {
                    const float z0 = ssv[idx] + sdv[hh2];
                    const float zr = fmaxf(z0, 0.2f * z0);
                    const float e = EXP2F(zr);
                    const float w = ((mw[idx] >> n) & 1u) ? e : 1.0f;
                    wt[idx] = __float_as_uint(w) & 0xffff0000u;   // bf16 trunc
                    zacc[hh2] += __uint_as_float(wt[idx]);
                }
                uintx4 au;
                au.x = __builtin_amdgcn_perm(wt[1], wt[0], 0x07060302);
                au.y = __builtin_amdgcn_perm(wt[3], wt[2], 0x07060302);
                au.z = __builtin_amdgcn_perm(wt[5], wt[4], 0x07060302);
                au.w = __builtin_amdgcn_perm(wt[7], wt[6], 0x07060302);
                Cacc[hh2] = __builtin_amdgcn_mfma_f32_16x16x32_bf16(
                    __builtin_bit_cast(short8, au), Bf[hh2], Cacc[hh2], 0, 0, 0);
            }
        }

        // Z: reduce over quads (lane's zacc covers dst = n), publish via
        // wave-private z_l rows (no barrier needed: rows h0,h0+1 are only
        // touched by this wave).
#pragma unroll
        for (int hh2 = 0; hh2 < 2; ++hh2) {
            float z = zacc[hh2];
            z += __shfl_xor(z, 16);
            z += __shfl_xor(z, 32);
            zacc[hh2] = z;
        }
        if (q == 0) { z_l[h0][n] = zacc[0]; z_l[h0 + 1][n] = zacc[1]; }

        // epilogue: hacc += C/Z + xp_self + bias (C row = dst q*4+reg, col f = n)
#pragma unroll
        for (int hh2 = 0; hh2 < 2; ++hh2) {
            const int h = h0 + hh2;
            const float bv = bias[ij * D_ + h * 16 + n];
            const uint2 sv = *(const uint2*)(xpi + (size_t)(h * 16 + n) * N_ + d0 + q * 4);
            const float selfv[4] = { bflo(sv.x), bfhi(sv.x), bflo(sv.y), bfhi(sv.y) };
#pragma unroll
            for (int reg = 0; reg < 4; ++reg) {
                const float Zi = 1.0f / z_l[h][q * 4 + reg];
                hacc[hh2][reg] += Cacc[hh2][reg] * Zi + selfv[reg] + bv;
            }
        }
    }

#pragma unroll
    for (int hh2 = 0; hh2 < 2; ++hh2)
#pragma unroll
        for (int reg = 0; reg < 4; ++reg)
            hout[((size_t)bi * N_ + d0 + q * 4 + reg) * D_ + (h0 + hh2) * 16 + n]
                = hacc[hh2][reg];
}

// ---------------------------------------------------------------------------
// Kernel 3: in-place mix on d_out (thread owns both i slices of one b).
// ---------------------------------------------------------------------------
__global__ __launch_bounds__(256) void combine_kernel(float* __restrict__ h)
{
    const int idx = blockIdx.x * 256 + threadIdx.x;
    const int b = idx >> 14;
    const int r = idx & 16383;
    float4* p0 = (float4*)h + (size_t)b * 32768 + r;
    float4* p1 = p0 + 16384;
    const float4 a = *p0;
    const float4 o = *p1;
    float4 r0, r1;
    r0.x = 1.5f * a.x + 0.5f * o.x;  r1.x = 1.5f * o.x + 0.5f * a.x;
    r0.y = 1.5f * a.y + 0.5f * o.y;  r1.y = 1.5f * o.y + 0.5f * a.y;
    r0.z = 1.5f * a.z + 0.5f * o.z;  r1.z = 1.5f * o.z + 0.5f * a.z;
    r0.w = 1.5f * a.w + 0.5f * o.w;  r1.w = 1.5f * o.w + 0.5f * a.w;
    *p0 = r0;
    *p1 = r1;
}

extern "C" void kernel_launch(void* const* d_in, const int* in_sizes, int n_in,
                              void* d_out, int out_size, void* d_ws, size_t ws_size,
                              hipStream_t stream)
{
    const float* x   = (const float*)d_in[0];
    const int*   A   = (const int*)d_in[1];
    const float* W   = (const float*)d_in[2];
    const float* pb  = (const float*)d_in[3];
    const float* as_ = (const float*)d_in[4];
    const float* ad_ = (const float*)d_in[5];
    const float* bs  = (const float*)d_in[6];

    unsigned short* xpt = (unsigned short*)d_ws;   // 8,388,608 B
    float* h = (float*)d_out;

    proj_kernel<<<dim3(8, 64), 256, 0, stream>>>(x, W, pb, xpt);
    attn_kernel<<<dim3(32, 32), 256, 0, stream>>>(xpt, A, as_, ad_, bs, h);
    combine_kernel<<<1024, 256, 0, stream>>>(h);
}